// Round 1
// baseline (170.609 us; speedup 1.0000x reference)
//
#include <hip/hip_runtime.h>

// BlockConvolutionLean: out = blockwise-exclusive-cumsum(X @ W^T) + b_eff
// X: [65536, 256] fp32, W: [256, 256] fp32, bias: [8] fp32, out: [65536, 256] fp32
//
// R4 theory: R3's traffic is minimal (66+64 MB) but BW is 2.37 TB/s with all
// pipes idle -> latency-bound. Culprit: vmcnt retires IN ORDER, and the B
// (L2-resident W) fragment loads were issued AFTER stage(c+1); waiting on B
// for the MFMAs therefore drained stage(c+1)'s HBM loads every iteration,
// collapsing the A-pipeline to depth ~1 (serial ~900cy HBM round trip/iter).
// R4: double-buffer B in registers, prefetched one chunk ahead, and issue
// Bpre(c+1) + STAGE(c+2) BEFORE the wait-for-stage(c). The top wait then
// leaves 24 VMEM ops (B(c), s(c+1), B(c+1), s(c+2)) in flight, and the MFMA's
// auto-wait for B(c) (issued a full iter earlier) drains no HBM stage.
// K-loop is macro-peeled so s_waitcnt immediates stay literal.

typedef short short8 __attribute__((ext_vector_type(8)));
typedef float floatx4 __attribute__((ext_vector_type(4)));
typedef unsigned short ushort4v __attribute__((ext_vector_type(4)));

typedef const __attribute__((address_space(1))) unsigned int* gas_u32p;
typedef __attribute__((address_space(3))) unsigned int* las_u32p;

// s_waitcnt with only vmcnt constrained (gfx9 encoding: vm[3:0]|[15:14],
// exp[6:4]=7, lgkm[11:8]=15)
#define WAIT_VMCNT(n) __builtin_amdgcn_s_waitcnt(0x0F70 | ((n) & 0xF) | ((((n) >> 4) & 0x3) << 14))

__device__ __forceinline__ void gl2lds16(const float* g, float* l) {
    __builtin_amdgcn_global_load_lds((gas_u32p)(const void*)g, (las_u32p)(void*)l, 16, 0, 0);
}

__device__ __forceinline__ unsigned short f2bf(float f) {
    union { float f; unsigned int u; } v;
    v.f = f;
    unsigned int u = v.u + 0x7fffu + ((v.u >> 16) & 1u);  // RNE to bf16
    return (unsigned short)(u >> 16);
}

__device__ __forceinline__ short8 pack8(float4 f0, float4 f1) {
    short8 r;
    r[0] = (short)f2bf(f0.x); r[1] = (short)f2bf(f0.y);
    r[2] = (short)f2bf(f0.z); r[3] = (short)f2bf(f0.w);
    r[4] = (short)f2bf(f1.x); r[5] = (short)f2bf(f1.y);
    r[6] = (short)f2bf(f1.z); r[7] = (short)f2bf(f1.w);
    return r;
}

// ---- Kernel 1: W fp32 -> bf16 into workspace ----
__global__ __launch_bounds__(256) void wconv_kernel(
    const float* __restrict__ W, unsigned short* __restrict__ Wb)
{
    const int i = (blockIdx.x * 256 + threadIdx.x) * 4;
    float4 f = *(const float4*)(W + i);
    ushort4v v;
    v[0] = f2bf(f.x); v[1] = f2bf(f.y); v[2] = f2bf(f.z); v[3] = f2bf(f.w);
    *(ushort4v*)(Wb + i) = v;
}

// ---- Kernel 2: GEMM + blockwise exclusive cumsum epilogue ----
// Block: 256 thr = 4 waves. Block tile M=128 x N=128; wave = 32-row strip
// (rows mg*128 + w*32, all 128 cols). acc: 2 mt x 8 nt x f32x4 = 64 AGPR.
__global__ __launch_bounds__(256, 3) void bcl_gemm_kernel(
    const float* __restrict__ X, const unsigned short* __restrict__ Wb,
    const float* __restrict__ bias, float* __restrict__ out)
{
    __shared__ float buf[3][128 * 32];   // 3 x 16 KB chunk buffers [128 rows][32 K]

    const int tid  = threadIdx.x;
    const int lane = tid & 63;
    const int w    = tid >> 6;          // wave 0..3
    const int bx   = blockIdx.x;
    const int mg   = bx >> 1;           // 0..511
    const int ng   = bx & 1;            // N-half

    const int cl = lane & 15;
    const int q  = lane >> 4;

    // Staging geometry: per round j, wave covers 8 rows x 128B (full lines).
    // lane i -> row i>>3, 16B segment (i&7)^(i>>3)  [source-gather swizzle:
    // physical LDS slot p of row r holds logical slot p ^ (r&7)].
    const int srow = lane >> 3;
    const int sseg = (lane & 7) ^ srow;
    const float* gsrc0 = X + (size_t)(mg * 128 + w * 32 + srow) * 256 + sseg * 4;

    // chunk c staged into given buffer; rounds j=0..3 cover rows w*32+j*8..+8
#define STAGE(c, b)                                                            \
    do {                                                                       \
        const float* _g = gsrc0 + (c) * 32;                                    \
        _Pragma("unroll")                                                      \
        for (int _j = 0; _j < 4; ++_j)                                         \
            gl2lds16(_g + _j * 8 * 256, &buf[b][(w * 32 + _j * 8) * 32]);      \
    } while (0)

    // B fragment: lane holds Wb[n = nt*16+cl][k = c*32 + q*8 ..+8] (16B load)
    const unsigned short* bBase = Wb + (size_t)(ng * 128 + cl) * 256 + q * 8;

    floatx4 acc[2][8];
    #pragma unroll
    for (int mt = 0; mt < 2; ++mt)
        #pragma unroll
        for (int nt = 0; nt < 8; ++nt)
            acc[mt][nt] = (floatx4){0.f, 0.f, 0.f, 0.f};

    short8 Bf[2][8];

    // Prologue issue order: s0, B0, s1 (so waiting on s0 keeps B0+s1 in
    // flight, and waiting on B0 later never drains s1).
    STAGE(0, 0);
    #pragma unroll
    for (int nt = 0; nt < 8; ++nt)
        Bf[0][nt] = *(const short8*)(bBase + nt * 16 * 256);
    STAGE(1, 1);

    // One K step, fully static (c is a literal). ALLOW = VMEM ops permitted
    // to remain outstanding while stage(c) completes:
    //   B(c)=8, plus [s(c+1)=4 + B(c+1)=8] if c<7, plus [s(c+2)=4] if c<6.
    //   c<=5: 24, c==6: 20, c==7: 8.
#define KSTEP(c, ALLOW)                                                        \
    do {                                                                       \
        if ((c) + 1 < 8) {                                                     \
            _Pragma("unroll")                                                  \
            for (int nt = 0; nt < 8; ++nt)                                     \
                Bf[((c) + 1) & 1][nt] = *(const short8*)                       \
                    (bBase + nt * 16 * 256 + ((c) + 1) * 32);                  \
        }                                                                      \
        if ((c) + 2 < 8) STAGE((c) + 2, ((c) + 2) % 3);                        \
        __builtin_amdgcn_sched_barrier(0);                                     \
        WAIT_VMCNT(ALLOW);                                                     \
        __builtin_amdgcn_sched_barrier(0);                                     \
        float4 af[2][2];                                                       \
        _Pragma("unroll")                                                      \
        for (int mt = 0; mt < 2; ++mt)                                         \
            _Pragma("unroll")                                                  \
            for (int h = 0; h < 2; ++h)                                        \
                af[mt][h] = *(const float4*)                                   \
                    &buf[(c) % 3][(w * 32 + mt * 16 + cl) * 32 +               \
                                  ((((q << 1) | h) ^ (cl & 7)) << 2)];         \
        short8 a0 = pack8(af[0][0], af[0][1]);                                 \
        short8 a1 = pack8(af[1][0], af[1][1]);                                 \
        _Pragma("unroll")                                                      \
        for (int nt = 0; nt < 8; ++nt) {                                       \
            acc[0][nt] = __builtin_amdgcn_mfma_f32_16x16x32_bf16(              \
                a0, Bf[(c) & 1][nt], acc[0][nt], 0, 0, 0);                     \
            acc[1][nt] = __builtin_amdgcn_mfma_f32_16x16x32_bf16(              \
                a1, Bf[(c) & 1][nt], acc[1][nt], 0, 0, 0);                     \
        }                                                                      \
    } while (0)

    KSTEP(0, 24);
    KSTEP(1, 24);
    KSTEP(2, 24);
    KSTEP(3, 24);
    KSTEP(4, 24);
    KSTEP(5, 24);
    KSTEP(6, 20);
    KSTEP(7, 8);
#undef KSTEP

    // ---- Epilogue: cumsum + bias, transpose via wave-private LDS, stream out
    // C/D layout: col = cl, tile-row = q*4 + reg; row%8 = (q&1)*4 + reg.
    float be[4];
    {
        const int off = (q & 1) * 4;
        be[0] = bias[off + 0];
        be[1] = bias[off + 1];
        be[2] = bias[off + 2];
        be[3] = bias[off + 3];
        if (off == 0) be[0] += bias[0];   // b_eff[0] = 2*bias[0]
    }

    float* epi = &buf[0][w * 32 * 32];   // wave-private 4 KB (8 rows x 128 f32)

    #pragma unroll
    for (int p = 0; p < 4; ++p) {        // 8-row group p: mt = p>>1, half = p&1
        const int mt = p >> 1;
        const bool act = ((q >> 1) == (p & 1));
        #pragma unroll
        for (int nt = 0; nt < 8; ++nt) {
            floatx4 v = acc[mt][nt];
            float p1 = v[0];
            float p2 = p1 + v[1];
            float p3 = p2 + v[2];
            float tot = p3 + v[3];
            float below = __shfl_up(tot, 16);   // previous quad's block total
            float p0 = 0.f;
            if (q & 1) { p0 = below; p1 += below; p2 += below; p3 += below; }
            if (act) {
                float* dst = epi + (q & 1) * 4 * 128 + nt * 16 + cl;
                dst[0]   = p0 + be[0];
                dst[128] = p1 + be[1];
                dst[256] = p2 + be[2];
                dst[384] = p3 + be[3];
            }
        }
        // read back rows, store contiguous 512B per out row (dwordx4 stream)
        #pragma unroll
        for (int k = 0; k < 4; ++k) {
            const int r   = k * 2 + (lane >> 5);   // 0..7
            const int c32 = lane & 31;
            floatx4 vv = *(const floatx4*)&epi[r * 128 + c32 * 4];
            const size_t grow = (size_t)(mg * 128 + w * 32 + p * 8 + r);
            *(floatx4*)&out[grow * 256 + ng * 128 + c32 * 4] = vv;
        }
    }
#undef STAGE
}

extern "C" void kernel_launch(void* const* d_in, const int* in_sizes, int n_in,
                              void* d_out, int out_size, void* d_ws, size_t ws_size,
                              hipStream_t stream)
{
    const float* X = (const float*)d_in[0];  // seq_vector [8*8192, 256]
    const float* W = (const float*)d_in[1];  // [256, 256]
    const float* B = (const float*)d_in[2];  // [8]
    float* out = (float*)d_out;              // [8*8192, 256]
    unsigned short* Wb = (unsigned short*)d_ws;  // 256*256 bf16 = 128 KB

    wconv_kernel<<<dim3(64), dim3(256), 0, stream>>>(W, Wb);
    bcl_gemm_kernel<<<dim3(1024), dim3(256), 0, stream>>>(X, Wb, B, out);
}

// Round 2
// 148.054 us; speedup vs baseline: 1.1523x; 1.1523x over previous
//
#include <hip/hip_runtime.h>

// BlockConvolutionLean: out = blockwise-exclusive-cumsum(X @ W^T) + b_eff
// X: [65536, 256] fp32, W: [256, 256] fp32, bias: [8] fp32, out: [65536, 256] fp32
//
// R5: R4's reg-double-buffered B spilled to scratch (+35 MB HBM traffic,
// 57->83us). Root cause kept: B fragment loads in the vmcnt queue force a
// mid-iteration wait that drains young HBM stages (in-order retirement).
// R5 removes B from BOTH the register file and the vmcnt queue:
//   - N split 4-ways (64 cols/block); block's B-half = 32 KB bf16 staged
//     into LDS ONCE at block start; per-iter B reads are ds_read_b128
//     (lgkmcnt domain, independent of stage queue). acc halves to 32 VGPR.
//   - A path unchanged from R3 (gl2lds full-line streams, 3-ring, XOR
//     source-gather swizzle, wave-private slabs, zero main-loop barriers),
//     but STAGE(c+2) issued at iter TOP -> single wait/iter for stage(c)
//     with 8 ops (c+1, c+2) left in flight = depth-2 HBM pipeline.
//   - B LDS XOR-swizzle phys_seg = logical ^ (n&15) (involution applied at
//     gl2lds source and at read) -> 2-way max bank aliasing (free).
// LDS 48 + 32 = 80 KB -> 2 blocks/CU; X read 4x but L3 absorbs (proven R3).

typedef short short8 __attribute__((ext_vector_type(8)));
typedef float floatx4 __attribute__((ext_vector_type(4)));
typedef unsigned short ushort4v __attribute__((ext_vector_type(4)));

typedef const __attribute__((address_space(1))) unsigned int* gas_u32p;
typedef __attribute__((address_space(3))) unsigned int* las_u32p;

// s_waitcnt with only vmcnt constrained (gfx9 encoding: vm[3:0]|[15:14],
// exp[6:4]=7, lgkm[11:8]=15)
#define WAIT_VMCNT(n) __builtin_amdgcn_s_waitcnt(0x0F70 | ((n) & 0xF) | ((((n) >> 4) & 0x3) << 14))

__device__ __forceinline__ void gl2lds16(const void* g, void* l) {
    __builtin_amdgcn_global_load_lds((gas_u32p)g, (las_u32p)l, 16, 0, 0);
}

__device__ __forceinline__ unsigned short f2bf(float f) {
    union { float f; unsigned int u; } v;
    v.f = f;
    unsigned int u = v.u + 0x7fffu + ((v.u >> 16) & 1u);  // RNE to bf16
    return (unsigned short)(u >> 16);
}

__device__ __forceinline__ short8 pack8(float4 f0, float4 f1) {
    short8 r;
    r[0] = (short)f2bf(f0.x); r[1] = (short)f2bf(f0.y);
    r[2] = (short)f2bf(f0.z); r[3] = (short)f2bf(f0.w);
    r[4] = (short)f2bf(f1.x); r[5] = (short)f2bf(f1.y);
    r[6] = (short)f2bf(f1.z); r[7] = (short)f2bf(f1.w);
    return r;
}

// ---- Kernel 1: W fp32 -> bf16 into workspace ----
__global__ __launch_bounds__(256) void wconv_kernel(
    const float* __restrict__ W, unsigned short* __restrict__ Wb)
{
    const int i = (blockIdx.x * 256 + threadIdx.x) * 4;
    float4 f = *(const float4*)(W + i);
    ushort4v v;
    v[0] = f2bf(f.x); v[1] = f2bf(f.y); v[2] = f2bf(f.z); v[3] = f2bf(f.w);
    *(ushort4v*)(Wb + i) = v;
}

// ---- Kernel 2: GEMM + blockwise exclusive cumsum epilogue ----
// Block: 256 thr = 4 waves. Block tile M=128 x N=64; wave = 32-row strip
// (rows mg*128 + w*32, cols ng*64..+64). acc: 2 mt x 4 nt x f32x4 = 32 regs.
__global__ __launch_bounds__(256, 2) void bcl_gemm_kernel(
    const float* __restrict__ X, const unsigned short* __restrict__ Wb,
    const float* __restrict__ bias, float* __restrict__ out)
{
    __shared__ float buf[3][128 * 32];       // 48 KB A ring: [128 rows][32 K]
    __shared__ unsigned short bW[64 * 256];  // 32 KB B half: [64 n][256 k] bf16

    const int tid  = threadIdx.x;
    const int lane = tid & 63;
    const int w    = tid >> 6;          // wave 0..3
    const int bx   = blockIdx.x;
    const int mg   = bx >> 2;           // 0..511
    const int ng   = bx & 3;            // N-quarter 0..3

    const int cl = lane & 15;
    const int q  = lane >> 4;

    // A staging geometry (unchanged from R3): per round j, wave covers
    // 8 rows x 128B full lines. lane i -> row i>>3, 16B seg (i&7)^(i>>3)
    // [source-gather swizzle: phys LDS slot p of row r holds logical p^(r&7)]
    const int srow = lane >> 3;
    const int sseg = (lane & 7) ^ srow;
    const float* gsrc0 = X + (size_t)(mg * 128 + w * 32 + srow) * 256 + sseg * 4;

#define STAGE(c, b)                                                            \
    do {                                                                       \
        const float* _g = gsrc0 + (c) * 32;                                    \
        _Pragma("unroll")                                                      \
        for (int _j = 0; _j < 4; ++_j)                                         \
            gl2lds16(_g + _j * 8 * 256, &buf[b][(w * 32 + _j * 8) * 32]);      \
    } while (0)

    // ---- One-time B stage: 32 KB = 256 thr x 8 ops x 16B (from L2).
    // LDS slot s = j*256 + tid holds row n = s>>5, phys seg s&31; the
    // global source segment is (s&31) ^ (n&15)  [involution swizzle].
    {
        #pragma unroll
        for (int j = 0; j < 8; ++j) {
            const int n    = j * 8 + w * 2 + (lane >> 5);     // row 0..63
            const int seg  = lane & 31;                       // phys 16B seg
            const int lseg = seg ^ (n & 15);                  // logical seg
            const unsigned short* g =
                Wb + (size_t)(ng * 64 + n) * 256 + lseg * 8;
            gl2lds16(g, &bW[(size_t)(j * 256 + w * 64) * 8]);
        }
    }

    STAGE(0, 0);
    STAGE(1, 1);
    WAIT_VMCNT(8);        // B landed (oldest); A stages 0,1 may stay in flight
    __syncthreads();      // bW visible to all waves

    floatx4 acc[2][4];
    #pragma unroll
    for (int mt = 0; mt < 2; ++mt)
        #pragma unroll
        for (int nt = 0; nt < 4; ++nt)
            acc[mt][nt] = (floatx4){0.f, 0.f, 0.f, 0.f};

    // One K step (c literal). Single wait per iter: retire stage(c), keep
    // stage(c+1)+stage(c+2) = 8 ops in flight (depth-2 HBM pipeline).
    // B fragments come from LDS (lgkmcnt) -> never interact with vmcnt.
#define KSTEP(c, ALLOW)                                                        \
    do {                                                                       \
        if ((c) + 2 < 8) STAGE((c) + 2, ((c) + 2) % 3);                        \
        __builtin_amdgcn_sched_barrier(0);                                     \
        WAIT_VMCNT(ALLOW);                                                     \
        __builtin_amdgcn_sched_barrier(0);                                     \
        short8 Bf[4];                                                          \
        _Pragma("unroll")                                                      \
        for (int nt = 0; nt < 4; ++nt)                                         \
            Bf[nt] = *(const short8*)                                          \
                &bW[(nt * 16 + cl) * 256 + ((((c) * 4 + q) ^ cl) * 8)];        \
        float4 af[2][2];                                                       \
        _Pragma("unroll")                                                      \
        for (int mt = 0; mt < 2; ++mt)                                         \
            _Pragma("unroll")                                                  \
            for (int h = 0; h < 2; ++h)                                        \
                af[mt][h] = *(const float4*)                                   \
                    &buf[(c) % 3][(w * 32 + mt * 16 + cl) * 32 +               \
                                  ((((q << 1) | h) ^ (cl & 7)) << 2)];         \
        short8 a0 = pack8(af[0][0], af[0][1]);                                 \
        short8 a1 = pack8(af[1][0], af[1][1]);                                 \
        _Pragma("unroll")                                                      \
        for (int nt = 0; nt < 4; ++nt) {                                       \
            acc[0][nt] = __builtin_amdgcn_mfma_f32_16x16x32_bf16(              \
                a0, Bf[nt], acc[0][nt], 0, 0, 0);                              \
            acc[1][nt] = __builtin_amdgcn_mfma_f32_16x16x32_bf16(              \
                a1, Bf[nt], acc[1][nt], 0, 0, 0);                              \
        }                                                                      \
    } while (0)

    KSTEP(0, 8);
    KSTEP(1, 8);
    KSTEP(2, 8);
    KSTEP(3, 8);
    KSTEP(4, 8);
    KSTEP(5, 8);
    KSTEP(6, 4);
    KSTEP(7, 0);
#undef KSTEP

    // ---- Epilogue: cumsum + bias, transpose via wave-private LDS, stream out
    // C/D layout: col = cl, tile-row = q*4 + reg; row%8 = (q&1)*4 + reg.
    float be[4];
    {
        const int off = (q & 1) * 4;
        be[0] = bias[off + 0];
        be[1] = bias[off + 1];
        be[2] = bias[off + 2];
        be[3] = bias[off + 3];
        if (off == 0) be[0] += bias[0];   // b_eff[0] = 2*bias[0]
    }

    float* epi = &buf[0][w * 32 * 32];   // wave-private 4 KB (8 rows x 64 f32)

    #pragma unroll
    for (int p = 0; p < 4; ++p) {        // 8-row group p: mt = p>>1, half = p&1
        const int mt = p >> 1;
        const bool act = ((q >> 1) == (p & 1));
        #pragma unroll
        for (int nt = 0; nt < 4; ++nt) {
            floatx4 v = acc[mt][nt];
            float p1 = v[0];
            float p2 = p1 + v[1];
            float p3 = p2 + v[2];
            float tot = p3 + v[3];
            float below = __shfl_up(tot, 16);   // previous quad's block total
            float p0 = 0.f;
            if (q & 1) { p0 = below; p1 += below; p2 += below; p3 += below; }
            if (act) {
                float* dst = epi + (q & 1) * 4 * 64 + nt * 16 + cl;
                dst[0]   = p0 + be[0];
                dst[64]  = p1 + be[1];
                dst[128] = p2 + be[2];
                dst[192] = p3 + be[3];
            }
        }
        // read back rows, store contiguous 256B per out row (dwordx4 stream)
        #pragma unroll
        for (int k = 0; k < 2; ++k) {
            const int r   = k * 4 + (lane >> 4);   // 0..7
            const int c16 = lane & 15;
            floatx4 vv = *(const floatx4*)&epi[r * 64 + c16 * 4];
            const size_t grow = (size_t)(mg * 128 + w * 32 + p * 8 + r);
            *(floatx4*)&out[grow * 256 + ng * 64 + c16 * 4] = vv;
        }
    }
#undef STAGE
}

extern "C" void kernel_launch(void* const* d_in, const int* in_sizes, int n_in,
                              void* d_out, int out_size, void* d_ws, size_t ws_size,
                              hipStream_t stream)
{
    const float* X = (const float*)d_in[0];  // seq_vector [8*8192, 256]
    const float* W = (const float*)d_in[1];  // [256, 256]
    const float* B = (const float*)d_in[2];  // [8]
    float* out = (float*)d_out;              // [8*8192, 256]
    unsigned short* Wb = (unsigned short*)d_ws;  // 256*256 bf16 = 128 KB

    wconv_kernel<<<dim3(64), dim3(256), 0, stream>>>(W, Wb);
    bcl_gemm_kernel<<<dim3(2048), dim3(256), 0, stream>>>(X, Wb, B, out);
}

// Round 3
// 141.411 us; speedup vs baseline: 1.2065x; 1.0470x over previous
//
#include <hip/hip_runtime.h>

// BlockConvolutionLean: out = blockwise-exclusive-cumsum(X @ W^T) + b_eff
// X: [65536, 256] fp32, W: [256, 256] fp32, bias: [8] fp32, out: [65536, 256] fp32
//
// R6: R5 fixed the vmcnt-drain (BW 2.37->3.48 TB/s) but was neutral in time:
// the 4-way N-split re-read X from HBM (FETCH 66->131 MB; the 4 siblings of
// each M-panel land on 4 DIFFERENT XCDs under round-robin dispatch, so each
// XCD-L2 misses separately), and occupancy stayed at 8 waves/CU (18%).
// R6 attacks both:
//   - XCD-sibling swizzle: xcd = bx&7 (round-robin), each XCD owns a
//     contiguous mg range; the 4 ng-siblings of an mg are CONSECUTIVE blocks
//     on the SAME XCD -> panel fetched once per L2, siblings hit L2 (off the
//     HBM/fabric path). FETCH should return to ~67 MB.
//   - 512-thread blocks (8 waves x 16 rows), same 80 KB LDS -> still
//     2 blocks/CU but 16 waves/CU (2x), per-CU outstanding DMA 64->96 KB.
//     Per-wave acc halves to 16 VGPR -> ~80 VGPR, launch_bounds(512,4).
// Main loop structure unchanged from R5: zero barriers, wave-private slabs,
// single WAIT_VMCNT per iter (retire stage c, keep c+1/c+2 in flight),
// B from LDS (lgkmcnt domain, never interacts with the stage queue).

typedef short short8 __attribute__((ext_vector_type(8)));
typedef float floatx4 __attribute__((ext_vector_type(4)));
typedef unsigned short ushort4v __attribute__((ext_vector_type(4)));

typedef const __attribute__((address_space(1))) unsigned int* gas_u32p;
typedef __attribute__((address_space(3))) unsigned int* las_u32p;

// s_waitcnt with only vmcnt constrained (gfx9 encoding: vm[3:0]|[15:14],
// exp[6:4]=7, lgkm[11:8]=15)
#define WAIT_VMCNT(n) __builtin_amdgcn_s_waitcnt(0x0F70 | ((n) & 0xF) | ((((n) >> 4) & 0x3) << 14))

__device__ __forceinline__ void gl2lds16(const void* g, void* l) {
    __builtin_amdgcn_global_load_lds((gas_u32p)g, (las_u32p)l, 16, 0, 0);
}

__device__ __forceinline__ unsigned short f2bf(float f) {
    union { float f; unsigned int u; } v;
    v.f = f;
    unsigned int u = v.u + 0x7fffu + ((v.u >> 16) & 1u);  // RNE to bf16
    return (unsigned short)(u >> 16);
}

__device__ __forceinline__ short8 pack8(float4 f0, float4 f1) {
    short8 r;
    r[0] = (short)f2bf(f0.x); r[1] = (short)f2bf(f0.y);
    r[2] = (short)f2bf(f0.z); r[3] = (short)f2bf(f0.w);
    r[4] = (short)f2bf(f1.x); r[5] = (short)f2bf(f1.y);
    r[6] = (short)f2bf(f1.z); r[7] = (short)f2bf(f1.w);
    return r;
}

// ---- Kernel 1: W fp32 -> bf16 into workspace ----
__global__ __launch_bounds__(256) void wconv_kernel(
    const float* __restrict__ W, unsigned short* __restrict__ Wb)
{
    const int i = (blockIdx.x * 256 + threadIdx.x) * 4;
    float4 f = *(const float4*)(W + i);
    ushort4v v;
    v[0] = f2bf(f.x); v[1] = f2bf(f.y); v[2] = f2bf(f.z); v[3] = f2bf(f.w);
    *(ushort4v*)(Wb + i) = v;
}

// ---- Kernel 2: GEMM + blockwise exclusive cumsum epilogue ----
// Block: 512 thr = 8 waves. Block tile M=128 x N=64; wave = 16-row strip
// (rows mg*128 + w*16, cols ng*64..+64). acc: 4 nt x f32x4 = 16 regs.
__global__ __launch_bounds__(512, 4) void bcl_gemm_kernel(
    const float* __restrict__ X, const unsigned short* __restrict__ Wb,
    const float* __restrict__ bias, float* __restrict__ out)
{
    __shared__ float buf[3][128 * 32];       // 48 KB A ring: [128 rows][32 K]
    __shared__ unsigned short bW[64 * 256];  // 32 KB B quarter: [64 n][256 k]

    const int tid  = threadIdx.x;
    const int lane = tid & 63;
    const int w    = tid >> 6;          // wave 0..7
    const int bx   = blockIdx.x;

    // XCD-sibling swizzle: round-robin dispatch puts bx&7 on XCD bx&7.
    // Each XCD owns mg in [xcd*64, xcd*64+64); the 4 ng-siblings of an mg
    // are consecutive blocks on the SAME XCD -> X panel is L2-shared.
    const int xcd = bx & 7;
    const int u   = bx >> 3;            // 0..255 within XCD
    const int mg  = xcd * 64 + (u >> 2);
    const int ng  = u & 3;              // N-quarter 0..3

    const int cl = lane & 15;
    const int q  = lane >> 4;

    // A staging: per op, wave covers 8 rows x 128B full lines.
    // lane i -> row i>>3, 16B seg (i&7)^(i>>3)  [source-gather swizzle:
    // phys LDS slot p of row r holds logical p^(r&7)]
    const int srow = lane >> 3;
    const int sseg = (lane & 7) ^ srow;
    const float* gsrc0 = X + (size_t)(mg * 128 + w * 16 + srow) * 256 + sseg * 4;

#define STAGE(c, b)                                                            \
    do {                                                                       \
        const float* _g = gsrc0 + (c) * 32;                                    \
        _Pragma("unroll")                                                      \
        for (int _j = 0; _j < 2; ++_j)                                         \
            gl2lds16(_g + _j * 8 * 256, &buf[b][(w * 16 + _j * 8) * 32]);      \
    } while (0)

    // ---- One-time B stage: 32 KB = 512 thr x 4 ops x 16B (from L2).
    // LDS slot s = j*512 + tid holds row n = s>>5, phys seg s&31; global
    // source segment is (s&31) ^ (n&15)  [involution swizzle].
    {
        #pragma unroll
        for (int j = 0; j < 4; ++j) {
            const int n    = j * 16 + (tid >> 5);             // row 0..63
            const int seg  = tid & 31;                        // phys 16B seg
            const int lseg = seg ^ (n & 15);                  // logical seg
            const unsigned short* g =
                Wb + (size_t)(ng * 64 + n) * 256 + lseg * 8;
            gl2lds16(g, &bW[(size_t)(j * 512 + w * 64) * 8]);
        }
    }

    STAGE(0, 0);
    STAGE(1, 1);
    WAIT_VMCNT(4);        // B (oldest 4) landed; A stages 0,1 stay in flight
    __syncthreads();      // bW visible to all waves

    floatx4 acc[4];
    #pragma unroll
    for (int nt = 0; nt < 4; ++nt)
        acc[nt] = (floatx4){0.f, 0.f, 0.f, 0.f};

    // One K step (c literal). Single wait per iter: retire stage(c)'s 2 ops,
    // keep stage(c+1)+stage(c+2) = 4 ops in flight (depth-2 HBM pipeline).
#define KSTEP(c, ALLOW)                                                        \
    do {                                                                       \
        if ((c) + 2 < 8) STAGE((c) + 2, ((c) + 2) % 3);                        \
        __builtin_amdgcn_sched_barrier(0);                                     \
        WAIT_VMCNT(ALLOW);                                                     \
        __builtin_amdgcn_sched_barrier(0);                                     \
        short8 Bf[4];                                                          \
        _Pragma("unroll")                                                      \
        for (int nt = 0; nt < 4; ++nt)                                         \
            Bf[nt] = *(const short8*)                                          \
                &bW[(nt * 16 + cl) * 256 + ((((c) * 4 + q) ^ cl) * 8)];        \
        float4 af[2];                                                          \
        _Pragma("unroll")                                                      \
        for (int h = 0; h < 2; ++h)                                            \
            af[h] = *(const float4*)                                           \
                &buf[(c) % 3][(w * 16 + cl) * 32 +                             \
                              ((((q << 1) | h) ^ (cl & 7)) << 2)];             \
        short8 a0 = pack8(af[0], af[1]);                                       \
        _Pragma("unroll")                                                      \
        for (int nt = 0; nt < 4; ++nt)                                         \
            acc[nt] = __builtin_amdgcn_mfma_f32_16x16x32_bf16(                 \
                a0, Bf[nt], acc[nt], 0, 0, 0);                                 \
    } while (0)

    KSTEP(0, 4);
    KSTEP(1, 4);
    KSTEP(2, 4);
    KSTEP(3, 4);
    KSTEP(4, 4);
    KSTEP(5, 4);
    KSTEP(6, 2);
    KSTEP(7, 0);
#undef KSTEP

    // ---- Epilogue: cumsum + bias, transpose via wave-private LDS, stream out
    // C/D layout: col = cl, tile-row = q*4 + reg; row%8 = (q&1)*4 + reg.
    float be[4];
    {
        const int off = (q & 1) * 4;
        be[0] = bias[off + 0];
        be[1] = bias[off + 1];
        be[2] = bias[off + 2];
        be[3] = bias[off + 3];
        if (off == 0) be[0] += bias[0];   // b_eff[0] = 2*bias[0]
    }

    // Wave-private epi: 8 rows x 64 f32 = 2 KB per half, carved from the
    // wave's OWN 16-row slab of buf[0] (p=0) and buf[1] (p=1) -> no barrier.
    float* epi0 = &buf[0][(w * 16) * 32];
    float* epi1 = &buf[1][(w * 16) * 32];

    #pragma unroll
    for (int p = 0; p < 2; ++p) {        // 8-row half p of the 16-row tile
        float* epi = p ? epi1 : epi0;
        const bool act = ((q >> 1) == p);
        #pragma unroll
        for (int nt = 0; nt < 4; ++nt) {
            floatx4 v = acc[nt];
            float p1 = v[0];
            float p2 = p1 + v[1];
            float p3 = p2 + v[2];
            float tot = p3 + v[3];
            float below = __shfl_up(tot, 16);   // previous quad's block total
            float p0 = 0.f;
            if (q & 1) { p0 = below; p1 += below; p2 += below; p3 += below; }
            if (act) {
                float* dst = epi + (q & 1) * 4 * 64 + nt * 16 + cl;
                dst[0]   = p0 + be[0];
                dst[64]  = p1 + be[1];
                dst[128] = p2 + be[2];
                dst[192] = p3 + be[3];
            }
        }
        // read back rows, store contiguous 256B per out row (dwordx4 stream)
        #pragma unroll
        for (int k = 0; k < 2; ++k) {
            const int r   = k * 4 + (lane >> 4);   // 0..7
            const int c16 = lane & 15;
            floatx4 vv = *(const floatx4*)&epi[r * 64 + c16 * 4];
            const size_t grow = (size_t)(mg * 128 + w * 16 + p * 8 + r);
            *(floatx4*)&out[grow * 256 + ng * 64 + c16 * 4] = vv;
        }
    }
#undef STAGE
}

extern "C" void kernel_launch(void* const* d_in, const int* in_sizes, int n_in,
                              void* d_out, int out_size, void* d_ws, size_t ws_size,
                              hipStream_t stream)
{
    const float* X = (const float*)d_in[0];  // seq_vector [8*8192, 256]
    const float* W = (const float*)d_in[1];  // [256, 256]
    const float* B = (const float*)d_in[2];  // [8]
    float* out = (float*)d_out;              // [8*8192, 256]
    unsigned short* Wb = (unsigned short*)d_ws;  // 256*256 bf16 = 128 KB

    wconv_kernel<<<dim3(64), dim3(256), 0, stream>>>(W, Wb);
    bcl_gemm_kernel<<<dim3(2048), dim3(512), 0, stream>>>(X, Wb, B, out);
}